// Round 1
// baseline (495.688 us; speedup 1.0000x reference)
//
#include <hip/hip_runtime.h>

#define SDIM 128
#define LDIM 8192
#define BATCH 32
#define TL 32      // q-rows per block
#define NW 4       // waves per block
#define RPW 8      // rows per wave

// ---------------- Kernel 1: ksum[b][j] = sum_d keys[b][j][d] ----------------
// One wave per (b,j) row: 4096 waves total.
__global__ void ksum_kernel(const float* __restrict__ keys, float* __restrict__ ksum) {
    int gwave = (blockIdx.x * blockDim.x + threadIdx.x) >> 6;  // row index b*128+j
    int lane = threadIdx.x & 63;
    const float* row = keys + (size_t)gwave * SDIM;
    float v = row[lane] + row[lane + 64];
    #pragma unroll
    for (int off = 32; off > 0; off >>= 1) v += __shfl_xor(v, off, 64);
    if (lane == 0) ksum[gwave] = v;
}

// ---------------- Kernel 2: fused scores -> softmax -> out ----------------
// scores = q @ Kp  with Kp[e][j] = keys[e][j] + ksum[j]
// A = softmax(scores, axis=-1);  out = A @ V
__global__ __launch_bounds__(256, 2) void attn_kernel(
        const float* __restrict__ q,
        const float* __restrict__ keys,
        const float* __restrict__ values,
        const float* __restrict__ ksum,
        float* __restrict__ out) {
    __shared__ float Kp[SDIM][SDIM];   // 64 KB; holds K' in phase 1, V in phase 2
    __shared__ float Qs[TL][SDIM];     // 16 KB; holds Q tile in phase 1, A in phase 2

    const int b    = blockIdx.x >> 8;          // 256 tiles per batch (8192/32)
    const int tile = blockIdx.x & 255;
    const int row0 = tile * TL;
    const int tid  = threadIdx.x;
    const int wave = tid >> 6;
    const int lane = tid & 63;

    const float* kb = keys   + (size_t)b * SDIM * SDIM;
    const float* vb = values + (size_t)b * SDIM * SDIM;
    const float* qb = q      + ((size_t)b * LDIM + row0) * SDIM;
    const float* ks = ksum   + b * SDIM;
    float*       ob = out    + ((size_t)b * LDIM + row0) * SDIM;

    // ---- Stage Kp = keys + ksum (broadcast over e), and Q tile ----
    {
        const float4* k4  = (const float4*)kb;
        const float4* ks4 = (const float4*)ks;
        float4* kp4 = (float4*)&Kp[0][0];
        #pragma unroll
        for (int i = 0; i < (SDIM * SDIM / 4) / 256; ++i) {   // 16 iters
            int c = tid + i * 256;
            float4 kv = k4[c];
            float4 sv = ks4[c & 31];     // j0/4 == c % 32
            kv.x += sv.x; kv.y += sv.y; kv.z += sv.z; kv.w += sv.w;
            kp4[c] = kv;
        }
        const float4* q4 = (const float4*)qb;
        float4* qs4 = (float4*)&Qs[0][0];
        #pragma unroll
        for (int i = 0; i < (TL * SDIM / 4) / 256; ++i) {     // 4 iters
            int c = tid + i * 256;
            qs4[c] = q4[c];
        }
    }
    __syncthreads();

    const int myrow = wave * RPW;
    const int col2  = 2 * lane;

    // ---- Phase 1: scores = q @ Kp, register-blocked 8 rows x 2 cols/lane ----
    float2 acc[RPW];
    #pragma unroll
    for (int r = 0; r < RPW; ++r) acc[r] = make_float2(0.f, 0.f);

    #pragma unroll 4
    for (int e = 0; e < SDIM; e += 4) {
        float2 kp0 = *(const float2*)&Kp[e + 0][col2];
        float2 kp1 = *(const float2*)&Kp[e + 1][col2];
        float2 kp2 = *(const float2*)&Kp[e + 2][col2];
        float2 kp3 = *(const float2*)&Kp[e + 3][col2];
        #pragma unroll
        for (int r = 0; r < RPW; ++r) {
            float4 qv = *(const float4*)&Qs[myrow + r][e];
            acc[r].x = fmaf(qv.x, kp0.x, acc[r].x);
            acc[r].y = fmaf(qv.x, kp0.y, acc[r].y);
            acc[r].x = fmaf(qv.y, kp1.x, acc[r].x);
            acc[r].y = fmaf(qv.y, kp1.y, acc[r].y);
            acc[r].x = fmaf(qv.z, kp2.x, acc[r].x);
            acc[r].y = fmaf(qv.z, kp2.y, acc[r].y);
            acc[r].x = fmaf(qv.w, kp3.x, acc[r].x);
            acc[r].y = fmaf(qv.w, kp3.y, acc[r].y);
        }
    }

    // ---- Softmax over 128 cols (2 in-lane + 64-lane shuffle reduce); A -> Qs ----
    #pragma unroll
    for (int r = 0; r < RPW; ++r) {
        float m = fmaxf(acc[r].x, acc[r].y);
        #pragma unroll
        for (int off = 32; off > 0; off >>= 1) m = fmaxf(m, __shfl_xor(m, off, 64));
        float ex = __expf(acc[r].x - m);
        float ey = __expf(acc[r].y - m);
        float s = ex + ey;
        #pragma unroll
        for (int off = 32; off > 0; off >>= 1) s += __shfl_xor(s, off, 64);
        float inv = 1.0f / s;
        *(float2*)&Qs[myrow + r][col2] = make_float2(ex * inv, ey * inv);
    }

    // ---- Restage V over Kp ----
    __syncthreads();
    {
        const float4* v4 = (const float4*)vb;
        float4* kp4 = (float4*)&Kp[0][0];
        #pragma unroll
        for (int i = 0; i < (SDIM * SDIM / 4) / 256; ++i) {
            int c = tid + i * 256;
            kp4[c] = v4[c];
        }
    }
    __syncthreads();

    // ---- Phase 2: out = A @ V (same structure as phase 1) ----
    float2 o[RPW];
    #pragma unroll
    for (int r = 0; r < RPW; ++r) o[r] = make_float2(0.f, 0.f);

    #pragma unroll 4
    for (int j = 0; j < SDIM; j += 4) {
        float2 v0 = *(const float2*)&Kp[j + 0][col2];
        float2 v1 = *(const float2*)&Kp[j + 1][col2];
        float2 v2 = *(const float2*)&Kp[j + 2][col2];
        float2 v3 = *(const float2*)&Kp[j + 3][col2];
        #pragma unroll
        for (int r = 0; r < RPW; ++r) {
            float4 a4 = *(const float4*)&Qs[myrow + r][j];
            o[r].x = fmaf(a4.x, v0.x, o[r].x);
            o[r].y = fmaf(a4.x, v0.y, o[r].y);
            o[r].x = fmaf(a4.y, v1.x, o[r].x);
            o[r].y = fmaf(a4.y, v1.y, o[r].y);
            o[r].x = fmaf(a4.z, v2.x, o[r].x);
            o[r].y = fmaf(a4.z, v2.y, o[r].y);
            o[r].x = fmaf(a4.w, v3.x, o[r].x);
            o[r].y = fmaf(a4.w, v3.y, o[r].y);
        }
    }

    #pragma unroll
    for (int r = 0; r < RPW; ++r) {
        *(float2*)&ob[(size_t)(myrow + r) * SDIM + col2] = o[r];
    }
}

extern "C" void kernel_launch(void* const* d_in, const int* in_sizes, int n_in,
                              void* d_out, int out_size, void* d_ws, size_t ws_size,
                              hipStream_t stream) {
    const float* q    = (const float*)d_in[0];
    const float* keys = (const float*)d_in[1];
    const float* vals = (const float*)d_in[2];
    float* out  = (float*)d_out;
    float* ksum = (float*)d_ws;   // BATCH*SDIM floats = 16 KB

    // ksum: one wave per (b,j) row -> 4096 waves -> 1024 blocks of 256
    ksum_kernel<<<(BATCH * SDIM * 64) / 256, 256, 0, stream>>>(keys, ksum);

    // fused attention: 256 tiles/batch * 32 batches = 8192 blocks
    attn_kernel<<<BATCH * (LDIM / TL), 256, 0, stream>>>(q, keys, vals, ksum, out);
}

// Round 2
// 275.625 us; speedup vs baseline: 1.7984x; 1.7984x over previous
//
#include <hip/hip_runtime.h>

#define SDIM 128
#define LDIM 8192
#define BATCH 32

// ws layout: [0:16K) ksum (32*128 f32); then per batch b at 16K + b*98304:
//   [0:32K) KpT_hi bf16, [32K:64K) KpT_lo bf16, [64K:96K) VT bf16
// KpT[j][e] = keys[e][j] + ksum[j]  (transposed, hi/lo split)
// VT[d][j]  = values[j][d]          (transposed)
// Row layout: 128 rows x 256 B; each row = 16 chunks of 16 B (8 bf16 = 8
// consecutive inner indices); chunk c stored at slot c ^ (row & 15)  (XOR
// swizzle -> conflict-free ds_read_b128 fragment reads).
#define WS_KSUM_BYTES 16384
#define WS_BATCH_BYTES 98304

typedef __attribute__((ext_vector_type(8))) short short8;
typedef __attribute__((ext_vector_type(16))) float float16;

static __device__ __forceinline__ unsigned short f2bf(float x) {
    union { float f; unsigned u; } v; v.f = x;
    unsigned r = v.u + 0x7fffu + ((v.u >> 16) & 1u);  // RNE
    return (unsigned short)(r >> 16);
}
static __device__ __forceinline__ float bf2f(unsigned short h) {
    union { unsigned u; float f; } v; v.u = ((unsigned)h) << 16; return v.f;
}

union S8U { short8 v; unsigned short u[8]; unsigned w[4]; };

static __device__ __forceinline__ float16 mfma_bf16(short8 a, short8 b, float16 c) {
    return __builtin_amdgcn_mfma_f32_32x32x16_bf16(a, b, c, 0, 0, 0);
}

// ---------------- Kernel 1: ksum[b][j] = sum_d keys[b][j][d] ----------------
__global__ void ksum_kernel(const float* __restrict__ keys, float* __restrict__ ksum) {
    int gwave = (blockIdx.x * blockDim.x + threadIdx.x) >> 6;  // b*128 + j
    int lane = threadIdx.x & 63;
    const float* row = keys + (size_t)gwave * SDIM;
    float v = row[lane] + row[lane + 64];
    #pragma unroll
    for (int off = 32; off > 0; off >>= 1) v += __shfl_xor(v, off, 64);
    if (lane == 0) ksum[gwave] = v;
}

// ------------- Kernel 2: build KpT_hi/lo and VT in ws (64 blocks) -----------
// blockIdx: b = blk>>1; which = blk&1 (0: keys -> KpT, 1: values -> VT).
// LDS temp holds the 128x128 f32 tile ROTATED: element (r,c) at
// T[r*128 + ((c + r) & 127)]  -> conflict-free row writes AND column reads.
__global__ __launch_bounds__(256) void prep_kernel(
        const float* __restrict__ keys, const float* __restrict__ values,
        const float* __restrict__ ksum, char* __restrict__ ws) {
    __shared__ float T[SDIM * SDIM];  // 64 KB
    const int b = blockIdx.x >> 1;
    const int which = blockIdx.x & 1;
    const int tid = threadIdx.x;
    const float* src = (which ? values : keys) + (size_t)b * SDIM * SDIM;

    for (int i = tid; i < SDIM * SDIM / 4; i += 256) {   // 16 float4 per thread
        int r = i >> 5;
        int c0 = (i & 31) * 4;
        float4 v = ((const float4*)src)[i];
        float f[4] = {v.x, v.y, v.z, v.w};
        #pragma unroll
        for (int k = 0; k < 4; ++k)
            T[r * SDIM + ((c0 + k + r) & 127)] = f[k];
    }
    __syncthreads();

    char* dst = ws + WS_KSUM_BYTES + (size_t)b * WS_BATCH_BYTES + (which ? 65536 : 0);
    const float* ksb = ksum + b * SDIM;

    if (which == 0) {
        // chunk (j, c): e = 8c..8c+7: x = T[e][j] + ksum[j]
        for (int idx = tid; idx < 2048; idx += 256) {
            int j = idx >> 4, c = idx & 15;
            float ks = ksb[j];
            S8U hi, lo;
            #pragma unroll
            for (int i2 = 0; i2 < 8; ++i2) {
                int e = c * 8 + i2;
                float x = T[e * SDIM + ((j + e) & 127)] + ks;
                unsigned short h = f2bf(x);
                hi.u[i2] = h;
                lo.u[i2] = f2bf(x - bf2f(h));
            }
            int off = j * 256 + ((c ^ (j & 15)) * 16);
            *(short8*)(dst + off) = hi.v;
            *(short8*)(dst + 32768 + off) = lo.v;
        }
    } else {
        // chunk (d, c): j = 8c..8c+7: x = values[j][d] = T[j][d]
        for (int idx = tid; idx < 2048; idx += 256) {
            int d = idx >> 4, c = idx & 15;
            S8U hv;
            #pragma unroll
            for (int i2 = 0; i2 < 8; ++i2) {
                int j = c * 8 + i2;
                hv.u[i2] = f2bf(T[j * SDIM + ((d + j) & 127)]);
            }
            int off = d * 256 + ((c ^ (d & 15)) * 16);
            *(short8*)(dst + off) = hv.v;
        }
    }
}

// ---------------- Kernel 3: fused MFMA attention ----------------
// Per block: 128 q-rows (4 waves x 32). Computes S^T = KpT(hi/lo) x Q^T(hi/lo)
// (3-pass bf16 split), in-register softmax over j, then out^T = VT x P^T with
// P^T fragments built from registers via 2 shfl_xor(32) per k-step.
__global__ __launch_bounds__(256, 2) void attn_kernel(
        const float* __restrict__ q, const char* __restrict__ ws,
        float* __restrict__ out) {
    __shared__ uint4 smem[4096];  // 64 KB: KpT_hi+lo in phase 1, VT in phase 2
    const int blk = blockIdx.x;
    const int b = blk >> 6;       // 64 tiles per batch
    const int tile = blk & 63;
    const int tid = threadIdx.x;
    const int wave = tid >> 6;
    const int lane = tid & 63;
    const int H = lane >> 5;      // half of wave
    const int ln = lane & 31;

    const char* wsb = ws + WS_KSUM_BYTES + (size_t)b * WS_BATCH_BYTES;
    const float* qb = q + ((size_t)b * LDIM + tile * 128 + wave * 32) * SDIM;
    float* ob = out + ((size_t)b * LDIM + tile * 128 + wave * 32) * SDIM;

    // ---- stage KpT_hi + KpT_lo (64 KB) ----
    {
        const uint4* s4 = (const uint4*)wsb;
        for (int i = tid; i < 4096; i += 256) smem[i] = s4[i];
    }
    __syncthreads();
    const char* sm = (const char*)smem;

    // ---- Phase 1: S^T tiles. acc[m]: j-tile m (j = 32m + ln), col l = wave*32 + ln
    float16 acc[4];
    #pragma unroll
    for (int m = 0; m < 4; ++m) acc[m] = (float16)(0.0f);

    #pragma unroll
    for (int ks = 0; ks < 8; ++ks) {
        // B operand: Q^T frag. lane n = ln -> q-row; k = 8H + i -> e
        const float* qp = qb + ln * SDIM + ks * 16 + H * 8;
        float4 f0 = *(const float4*)qp;
        float4 f1 = *(const float4*)(qp + 4);
        float f[8] = {f0.x, f0.y, f0.z, f0.w, f1.x, f1.y, f1.z, f1.w};
        S8U bh, bl;
        #pragma unroll
        for (int i = 0; i < 8; ++i) {
            unsigned short h = f2bf(f[i]);
            bh.u[i] = h;
            bl.u[i] = f2bf(f[i] - bf2f(h));
        }
        const int chunk = ((2 * ks + H) ^ (lane & 15)) * 16;  // e-chunk, swizzled
        #pragma unroll
        for (int m = 0; m < 4; ++m) {
            int roff = (m * 32 + ln) * 256 + chunk;   // row j = 32m + ln
            short8 ah = *(const short8*)(sm + roff);
            short8 al = *(const short8*)(sm + 32768 + roff);
            acc[m] = mfma_bf16(ah, bh.v, acc[m]);
            acc[m] = mfma_bf16(ah, bl.v, acc[m]);
            acc[m] = mfma_bf16(al, bh.v, acc[m]);
        }
    }

    // ---- Softmax over j (rows of S^T): 64 values in-lane + partner half ----
    float mx = -1e30f;
    #pragma unroll
    for (int m = 0; m < 4; ++m)
        #pragma unroll
        for (int r = 0; r < 16; ++r) mx = fmaxf(mx, acc[m][r]);
    mx = fmaxf(mx, __shfl_xor(mx, 32, 64));
    float sum = 0.0f;
    #pragma unroll
    for (int m = 0; m < 4; ++m)
        #pragma unroll
        for (int r = 0; r < 16; ++r) {
            float e = __expf(acc[m][r] - mx);
            acc[m][r] = e;
            sum += e;
        }
    sum += __shfl_xor(sum, 32, 64);
    const float inv = 1.0f / sum;

    // pack P^T to bf16 pairs: pk[m][rr] = bf16(reg 2rr) | bf16(reg 2rr+1)<<16
    unsigned pk[4][8];
    #pragma unroll
    for (int m = 0; m < 4; ++m)
        #pragma unroll
        for (int rr = 0; rr < 8; ++rr)
            pk[m][rr] = (unsigned)f2bf(acc[m][2 * rr] * inv) |
                        ((unsigned)f2bf(acc[m][2 * rr + 1] * inv) << 16);

    // ---- restage VT (32 KB) over KpT ----
    __syncthreads();
    {
        const uint4* s4 = (const uint4*)(wsb + 65536);
        for (int i = tid; i < 2048; i += 256) smem[i] = s4[i];
    }
    __syncthreads();

    // ---- Phase 2: out^T = VT x P^T ----
    float16 oacc[4];
    #pragma unroll
    for (int m = 0; m < 4; ++m) oacc[m] = (float16)(0.0f);

    #pragma unroll
    for (int t = 0; t < 8; ++t) {
        const int m = t >> 1;
        const int c = 4 * (t & 1);
        // B frag (P^T): k = 8H + cc, j = 16t + k; source reg r = 8(t&1)+(cc&3)+4H,
        // source half = cc>>2. Own-range regs + partner exchange via shfl_xor(32).
        unsigned p0 = pk[m][c], p1 = pk[m][c + 1], p2 = pk[m][c + 2], p3 = pk[m][c + 3];
        unsigned a0 = H ? p2 : p0, a1 = H ? p3 : p1;   // own half, my k-range
        unsigned s0 = H ? p0 : p2, s1 = H ? p1 : p3;   // partner's k-range (send)
        unsigned r0 = (unsigned)__shfl_xor((int)s0, 32, 64);
        unsigned r1 = (unsigned)__shfl_xor((int)s1, 32, 64);
        S8U bf;
        bf.w[0] = H ? r0 : a0;
        bf.w[1] = H ? r1 : a1;
        bf.w[2] = H ? a0 : r0;
        bf.w[3] = H ? a1 : r1;
        const int chunk = ((2 * t + H) ^ (lane & 15)) * 16;  // j-chunk, swizzled
        #pragma unroll
        for (int dm = 0; dm < 4; ++dm) {
            short8 af = *(const short8*)(sm + (dm * 32 + ln) * 256 + chunk);  // row d = 32dm+ln
            oacc[dm] = mfma_bf16(af, bf.v, oacc[dm]);
        }
    }

    // ---- Epilogue: out^T C-layout -> coalesced float4 stores ----
    // oacc[dm][r]: d = 32dm + (r&3) + 8(r>>2) + 4H, l = ln
    #pragma unroll
    for (int dm = 0; dm < 4; ++dm)
        #pragma unroll
        for (int g = 0; g < 4; ++g) {
            float4 v = make_float4(oacc[dm][4 * g], oacc[dm][4 * g + 1],
                                   oacc[dm][4 * g + 2], oacc[dm][4 * g + 3]);
            int d0 = dm * 32 + g * 8 + H * 4;
            *(float4*)(ob + ln * SDIM + d0) = v;
        }
}

extern "C" void kernel_launch(void* const* d_in, const int* in_sizes, int n_in,
                              void* d_out, int out_size, void* d_ws, size_t ws_size,
                              hipStream_t stream) {
    const float* q    = (const float*)d_in[0];
    const float* keys = (const float*)d_in[1];
    const float* vals = (const float*)d_in[2];
    float* out  = (float*)d_out;
    float* ksum = (float*)d_ws;
    char*  ws   = (char*)d_ws;   // needs ~3.02 MB

    ksum_kernel<<<(BATCH * SDIM * 64) / 256, 256, 0, stream>>>(keys, ksum);
    prep_kernel<<<BATCH * 2, 256, 0, stream>>>(keys, vals, ksum, ws);
    attn_kernel<<<BATCH * (LDIM / 128), 256, 0, stream>>>(q, ws, out);
}

// Round 3
// 275.103 us; speedup vs baseline: 1.8018x; 1.0019x over previous
//
#include <hip/hip_runtime.h>

#define SDIM 128
#define LDIM 8192
#define BATCH 32

// ws: per batch b at b*98304:
//   [0:32K)   KpT_hi  bf16, fragment-major: offset = ((m*8+ks)*64 + lane)*16
//             content at lane=H*32+ln: KpT[32m+ln][16ks+8H .. +7]
//   [32K:64K) KpT_lo  (same layout)
//   [64K:96K) VT      (same layout, m->dm, ks->t): VT[32dm+ln][16t+8H .. +7]
// KpT[j][e] = keys[e][j] + ksum[j],  ksum[j] = sum_d keys[j][d]
// VT[d][j]  = values[j][d]
#define WS_BATCH_BYTES 98304

typedef __attribute__((ext_vector_type(8))) short short8;
typedef __attribute__((ext_vector_type(16))) float float16;

union S8U { short8 v; unsigned short u[8]; unsigned w[4]; };
union FU { float f; unsigned u; };

static __device__ __forceinline__ unsigned short f2bf(float x) {
    FU v; v.f = x;
    unsigned r = v.u + 0x7fffu + ((v.u >> 16) & 1u);  // RNE
    return (unsigned short)(r >> 16);
}
static __device__ __forceinline__ float bf2f(unsigned short h) {
    FU v; v.u = ((unsigned)h) << 16; return v.f;
}
static __device__ __forceinline__ float16 mfma_bf16(short8 a, short8 b, float16 c) {
    return __builtin_amdgcn_mfma_f32_32x32x16_bf16(a, b, c, 0, 0, 0);
}

// ---------------- prep: build KpT_hi/lo and VT frags (+fused ksum) ----------
// grid = BATCH*4: b = blk>>2, which = (blk>>1)&1 (0:keys 1:values), half = blk&1
__global__ __launch_bounds__(256) void prep_kernel(
        const float* __restrict__ keys, const float* __restrict__ values,
        char* __restrict__ ws) {
    __shared__ float T[SDIM * SDIM];   // rotated: (r,c) at r*128 + ((c+r)&127)
    __shared__ float ksum_s[SDIM];
    const int blk = blockIdx.x;
    const int b = blk >> 2;
    const int which = (blk >> 1) & 1;
    const int half = blk & 1;
    const int tid = threadIdx.x;
    const float* src = (which ? values : keys) + (size_t)b * SDIM * SDIM;

    #pragma unroll
    for (int it = 0; it < 16; ++it) {
        int i = tid + it * 256;
        int r = i >> 5, c0 = (i & 31) * 4;
        float4 v = ((const float4*)src)[i];
        float f[4] = {v.x, v.y, v.z, v.w};
        #pragma unroll
        for (int k = 0; k < 4; ++k)
            T[r * SDIM + ((c0 + k + r) & 127)] = f[k];
    }
    __syncthreads();

    if (which == 0) {  // ksum[j] = row-sum of keys row j (rotation is a row-permutation)
        int row = tid >> 1, hf = tid & 1;
        float s = 0.f;
        #pragma unroll
        for (int i = 0; i < 64; ++i) s += T[row * SDIM + hf * 64 + i];
        s += __shfl_xor(s, 1, 64);
        if (hf == 0) ksum_s[row] = s;
    }
    __syncthreads();

    char* dst = ws + (size_t)b * WS_BATCH_BYTES + (which ? 65536 : 0);
    #pragma unroll
    for (int it = 0; it < 4; ++it) {
        int entry = half * 1024 + it * 256 + tid;   // (m*8+ks)*64 + lane
        int m = entry >> 9;
        int ks = (entry >> 6) & 7;
        int lane = entry & 63;
        int ln = lane & 31, H = lane >> 5;
        int r = 32 * m + ln;        // j (keys) or d (values)
        int c0 = 16 * ks + 8 * H;   // e0 (keys) or j0 (values)
        if (which == 0) {
            float add = ksum_s[r];
            S8U hi, lo;
            #pragma unroll
            for (int i = 0; i < 8; ++i) {
                int e = c0 + i;
                float x = T[e * SDIM + ((r + e) & 127)] + add;  // keys[e][r]+ksum
                unsigned short h = f2bf(x);
                hi.u[i] = h;
                lo.u[i] = f2bf(x - bf2f(h));
            }
            *(short8*)(dst + entry * 16) = hi.v;
            *(short8*)(dst + 32768 + entry * 16) = lo.v;
        } else {
            S8U hv;
            #pragma unroll
            for (int i = 0; i < 8; ++i) {
                int j = c0 + i;
                hv.u[i] = f2bf(T[j * SDIM + ((r + j) & 127)]);  // values[j][r]
            }
            *(short8*)(dst + entry * 16) = hv.v;
        }
    }
}

// ---------------- attn: single-barrier fused MFMA attention ----------------
__global__ __launch_bounds__(256, 2) void attn_kernel(
        const float* __restrict__ q, const char* __restrict__ ws,
        float* __restrict__ out) {
    __shared__ char smQ[65536];   // [0:32K) Q_hi frags (swizzled), [32K:64K) Q_lo
    const int blk = blockIdx.x;
    const int b = blk >> 6, tile = blk & 63;
    const int tid = threadIdx.x, wave = tid >> 6, lane = tid & 63;
    const int H = lane >> 5, ln = lane & 31;

    const char* wsb = ws + (size_t)b * WS_BATCH_BYTES;
    const float* qblk = q + ((size_t)b * LDIM + tile * 128) * SDIM;
    float* ob = out + ((size_t)b * LDIM + tile * 128 + wave * 32) * SDIM;

    // ---- stage Q tile coalesced -> bf16 hi/lo -> swizzled LDS chunks ----
    {
        float4 buf[8][2];
        #pragma unroll
        for (int it = 0; it < 8; ++it) {
            int idx = it * 256 + tid;
            const float* p = qblk + (idx >> 4) * SDIM + (idx & 15) * 8;
            buf[it][0] = *(const float4*)p;
            buf[it][1] = *(const float4*)(p + 4);
        }
        #pragma unroll
        for (int it = 0; it < 8; ++it) {
            int idx = it * 256 + tid;
            int row = idx >> 4, cc = idx & 15;
            float f[8] = {buf[it][0].x, buf[it][0].y, buf[it][0].z, buf[it][0].w,
                          buf[it][1].x, buf[it][1].y, buf[it][1].z, buf[it][1].w};
            unsigned hiw[4], low[4];
            #pragma unroll
            for (int pr = 0; pr < 4; ++pr) {
                FU u0, u1; u0.f = f[2 * pr]; u1.f = f[2 * pr + 1];
                unsigned r0 = u0.u + 0x7fffu + ((u0.u >> 16) & 1u);
                unsigned r1 = u1.u + 0x7fffu + ((u1.u >> 16) & 1u);
                hiw[pr] = (r0 >> 16) | (r1 & 0xffff0000u);
                FU h0, h1; h0.u = r0 & 0xffff0000u; h1.u = r1 & 0xffff0000u;
                FU l0, l1; l0.f = f[2 * pr] - h0.f; l1.f = f[2 * pr + 1] - h1.f;
                low[pr] = (l0.u >> 16) | (l1.u & 0xffff0000u);  // trunc lo
            }
            int off = row * 256 + ((cc ^ (row & 15)) * 16);
            *(uint4*)(smQ + off) = make_uint4(hiw[0], hiw[1], hiw[2], hiw[3]);
            *(uint4*)(smQ + 32768 + off) = make_uint4(low[0], low[1], low[2], low[3]);
        }
    }
    __syncthreads();

    const char* qrp = smQ + (wave * 32 + ln) * 256;  // this lane's q-row (hi); lo +32768
    const char* kph = wsb;
    const char* kpl = wsb + 32768;
    const char* vtf = wsb + 65536;
    const int lo16 = lane * 16;

    // ---- Phase 1: S^T = KpT x Q^T, 3-pass bf16 split, A-frags from L2 ----
    float16 acc[4];
    #pragma unroll
    for (int m = 0; m < 4; ++m) acc[m] = (float16)(0.0f);

    short8 ah[2][4], al[2][4];
    #pragma unroll
    for (int m = 0; m < 4; ++m) {
        ah[0][m] = *(const short8*)(kph + (m * 8) * 1024 + lo16);
        al[0][m] = *(const short8*)(kpl + (m * 8) * 1024 + lo16);
    }
    #pragma unroll
    for (int ks = 0; ks < 8; ++ks) {
        const int cur = ks & 1, nxt = cur ^ 1;
        if (ks < 7) {
            #pragma unroll
            for (int m = 0; m < 4; ++m) {
                ah[nxt][m] = *(const short8*)(kph + (m * 8 + ks + 1) * 1024 + lo16);
                al[nxt][m] = *(const short8*)(kpl + (m * 8 + ks + 1) * 1024 + lo16);
            }
        }
        int slot = ((2 * ks + H) ^ (ln & 15)) * 16;
        short8 bh = *(const short8*)(qrp + slot);
        short8 bl = *(const short8*)(qrp + 32768 + slot);
        #pragma unroll
        for (int m = 0; m < 4; ++m) acc[m] = mfma_bf16(ah[cur][m], bh, acc[m]);
        #pragma unroll
        for (int m = 0; m < 4; ++m) acc[m] = mfma_bf16(ah[cur][m], bl, acc[m]);
        #pragma unroll
        for (int m = 0; m < 4; ++m) acc[m] = mfma_bf16(al[cur][m], bh, acc[m]);
    }

    // ---- prefetch VT t=0 before softmax ----
    short8 av[2][4];
    #pragma unroll
    for (int dm = 0; dm < 4; ++dm)
        av[0][dm] = *(const short8*)(vtf + (dm * 8) * 1024 + lo16);

    // ---- softmax over j: 64 in-lane + partner half ----
    float mx = -1e30f;
    #pragma unroll
    for (int m = 0; m < 4; ++m)
        #pragma unroll
        for (int r = 0; r < 16; ++r) mx = fmaxf(mx, acc[m][r]);
    mx = fmaxf(mx, __shfl_xor(mx, 32, 64));
    float sum = 0.0f;
    #pragma unroll
    for (int m = 0; m < 4; ++m)
        #pragma unroll
        for (int r = 0; r < 16; ++r) {
            float e = __expf(acc[m][r] - mx);
            acc[m][r] = e;
            sum += e;
        }
    sum += __shfl_xor(sum, 32, 64);
    const float inv = 1.0f / sum;

    unsigned pk[4][8];
    #pragma unroll
    for (int m = 0; m < 4; ++m)
        #pragma unroll
        for (int rr = 0; rr < 8; ++rr)
            pk[m][rr] = (unsigned)f2bf(acc[m][2 * rr] * inv) |
                        ((unsigned)f2bf(acc[m][2 * rr + 1] * inv) << 16);

    // ---- Phase 2: out^T = VT x P^T (P^T frags from regs via 2 shuffles) ----
    float16 oacc[4];
    #pragma unroll
    for (int m = 0; m < 4; ++m) oacc[m] = (float16)(0.0f);

    #pragma unroll
    for (int t = 0; t < 8; ++t) {
        const int cur = t & 1, nxt = cur ^ 1;
        if (t < 7) {
            #pragma unroll
            for (int dm = 0; dm < 4; ++dm)
                av[nxt][dm] = *(const short8*)(vtf + (dm * 8 + t + 1) * 1024 + lo16);
        }
        const int m = t >> 1;
        const int c = 4 * (t & 1);
        unsigned p0 = pk[m][c], p1 = pk[m][c + 1], p2 = pk[m][c + 2], p3 = pk[m][c + 3];
        unsigned a0 = H ? p2 : p0, a1 = H ? p3 : p1;
        unsigned s0 = H ? p0 : p2, s1 = H ? p1 : p3;
        unsigned r0 = (unsigned)__shfl_xor((int)s0, 32, 64);
        unsigned r1 = (unsigned)__shfl_xor((int)s1, 32, 64);
        S8U bf;
        bf.w[0] = H ? r0 : a0;
        bf.w[1] = H ? r1 : a1;
        bf.w[2] = H ? a0 : r0;
        bf.w[3] = H ? a1 : r1;
        #pragma unroll
        for (int dm = 0; dm < 4; ++dm)
            oacc[dm] = mfma_bf16(av[cur][dm], bf.v, oacc[dm]);
    }

    // ---- epilogue: out^T C-layout -> coalesced float4 stores ----
    #pragma unroll
    for (int dm = 0; dm < 4; ++dm)
        #pragma unroll
        for (int g = 0; g < 4; ++g) {
            float4 v = make_float4(oacc[dm][4 * g], oacc[dm][4 * g + 1],
                                   oacc[dm][4 * g + 2], oacc[dm][4 * g + 3]);
            *(float4*)(ob + ln * SDIM + dm * 32 + g * 8 + H * 4) = v;
        }
}

extern "C" void kernel_launch(void* const* d_in, const int* in_sizes, int n_in,
                              void* d_out, int out_size, void* d_ws, size_t ws_size,
                              hipStream_t stream) {
    const float* q    = (const float*)d_in[0];
    const float* keys = (const float*)d_in[1];
    const float* vals = (const float*)d_in[2];
    float* out = (float*)d_out;
    char*  ws  = (char*)d_ws;   // needs 3 MB

    prep_kernel<<<BATCH * 4, 256, 0, stream>>>(keys, vals, ws);
    attn_kernel<<<BATCH * (LDIM / 128), 256, 0, stream>>>(q, ws, out);
}

// Round 4
// 267.623 us; speedup vs baseline: 1.8522x; 1.0280x over previous
//
#include <hip/hip_runtime.h>

#define SDIM 128
#define LDIM 8192
#define BATCH 32

// ws: per batch b at b*65536: [0:32K) KT fp16 frag-major, [32K:64K) VT fp16.
//   frag entry = (m*8+ks)*64 + lane, 16 B each; content at lane=H*32+ln:
//   KT: keys[16ks+8H .. +7][32m+ln]   VT: values[16ks+8H .. +7][32m+ln]
// ksum fp32 at WS_KSUM_OFF + b*512: ksum[j] = sum_d keys[j][d]
#define WS_KV_STRIDE 65536
#define WS_KSUM_OFF (BATCH * WS_KV_STRIDE)

typedef __attribute__((ext_vector_type(8))) _Float16 half8;
typedef __attribute__((ext_vector_type(16))) float float16;

union H8U { half8 v; _Float16 h[8]; unsigned w[4]; };
union PU { _Float16 h[2]; unsigned u; };

static __device__ __forceinline__ float16 mfma_f16(half8 a, half8 b, float16 c) {
    return __builtin_amdgcn_mfma_f32_32x32x16_f16(a, b, c, 0, 0, 0);
}

// ---------------- prep: KT / VT fp16 frags + ksum ----------------
// grid = BATCH*2: b = blk>>1, which = blk&1 (0: keys, 1: values)
__global__ __launch_bounds__(256) void prep_kernel(
        const float* __restrict__ keys, const float* __restrict__ values,
        char* __restrict__ ws) {
    __shared__ float T[SDIM * SDIM];   // rotated: (r,c) at r*128 + ((c+r)&127)
    const int b = blockIdx.x >> 1;
    const int which = blockIdx.x & 1;
    const int tid = threadIdx.x;
    const float* src = (which ? values : keys) + (size_t)b * SDIM * SDIM;

    #pragma unroll
    for (int it = 0; it < 16; ++it) {
        int i = tid + it * 256;
        int r = i >> 5, c0 = (i & 31) * 4;
        float4 v = ((const float4*)src)[i];
        float f[4] = {v.x, v.y, v.z, v.w};
        #pragma unroll
        for (int k = 0; k < 4; ++k)
            T[r * SDIM + ((c0 + k + r) & 127)] = f[k];
    }
    __syncthreads();

    if (which == 0 && tid < SDIM) {
        // row sum of keys row `tid` (rotation permutes within the row only)
        const float4* row = (const float4*)&T[tid * SDIM];
        float s = 0.f;
        #pragma unroll
        for (int i = 0; i < 32; ++i) { float4 v = row[i]; s += v.x + v.y + v.z + v.w; }
        ((float*)(ws + WS_KSUM_OFF + b * 512))[tid] = s;
    }

    char* dst = ws + (size_t)b * WS_KV_STRIDE + (which ? 32768 : 0);
    #pragma unroll
    for (int it = 0; it < 8; ++it) {
        int entry = it * 256 + tid;            // (m*8+ks)*64 + lane
        int lane = entry & 63, ln = lane & 31, H = lane >> 5;
        int m = entry >> 9, ks = (entry >> 6) & 7;
        int r = 32 * m + ln;                   // j (KT) or d (VT)
        int c0 = 16 * ks + 8 * H;              // e (KT) or j (VT)
        H8U o;
        #pragma unroll
        for (int i = 0; i < 8; ++i) {
            int c = c0 + i;
            o.h[i] = (_Float16)T[c * SDIM + ((r + c) & 127)];  // src[c][r]
        }
        *(half8*)(dst + entry * 16) = o.v;
    }
}

// ---------------- attn: fp16 MFMA + exact fp32 rank-1 score term ----------------
__global__ __launch_bounds__(256, 4) void attn_kernel(
        const float* __restrict__ q, const char* __restrict__ ws,
        float* __restrict__ out) {
    __shared__ char smQ[32768];     // Q fp16 frags, swizzled
    __shared__ float qsum_s[SDIM];
    __shared__ float ksum_s[SDIM];
    const int blk = blockIdx.x;
    const int b = blk >> 6, tile = blk & 63;
    const int tid = threadIdx.x, wave = tid >> 6, lane = tid & 63;
    const int H = lane >> 5, ln = lane & 31;

    const char* wsb = ws + (size_t)b * WS_KV_STRIDE;
    const float* qblk = q + ((size_t)b * LDIM + tile * 128) * SDIM;
    float* ob = out + ((size_t)b * LDIM + tile * 128 + wave * 32) * SDIM;

    if (tid < 32)
        ((float4*)ksum_s)[tid] = ((const float4*)(ws + WS_KSUM_OFF + b * 512))[tid];

    // ---- stage Q coalesced -> fp16 frags in LDS; fold per-row qsum ----
    {
        float4 bufA[4][2], bufB[4][2];
        #pragma unroll
        for (int it = 0; it < 4; ++it) {
            int idx = it * 256 + tid;
            const float* p = qblk + (idx >> 4) * SDIM + (idx & 15) * 8;
            bufA[it][0] = *(const float4*)p;
            bufA[it][1] = *(const float4*)(p + 4);
        }
        #pragma unroll
        for (int it = 0; it < 4; ++it) {
            int idx = (it + 4) * 256 + tid;
            const float* p = qblk + (idx >> 4) * SDIM + (idx & 15) * 8;
            bufB[it][0] = *(const float4*)p;
            bufB[it][1] = *(const float4*)(p + 4);
        }
        #pragma unroll
        for (int g = 0; g < 2; ++g) {
            #pragma unroll
            for (int it2 = 0; it2 < 4; ++it2) {
                int it = g * 4 + it2;
                int idx = it * 256 + tid;
                int row = idx >> 4, cc = idx & 15;
                float4 v0 = g ? bufB[it2][0] : bufA[it2][0];
                float4 v1 = g ? bufB[it2][1] : bufA[it2][1];
                float f[8] = {v0.x, v0.y, v0.z, v0.w, v1.x, v1.y, v1.z, v1.w};
                float s = f[0] + f[1] + f[2] + f[3] + f[4] + f[5] + f[6] + f[7];
                s += __shfl_xor(s, 1, 64);
                s += __shfl_xor(s, 2, 64);
                s += __shfl_xor(s, 4, 64);
                s += __shfl_xor(s, 8, 64);
                if ((tid & 15) == 0) qsum_s[row] = s;
                H8U hv;
                #pragma unroll
                for (int i = 0; i < 8; ++i) hv.h[i] = (_Float16)f[i];
                *(half8*)(smQ + row * 256 + ((cc ^ (row & 15)) * 16)) = hv.v;
            }
        }
    }
    __syncthreads();

    const char* qrp = smQ + (wave * 32 + ln) * 256;  // this lane's q-row frags
    const char* ktp = wsb;                           // KT frags (L1/L2)
    const char* vtp = wsb + 32768;                   // VT frags
    const int lo16 = lane * 16;

    // ---- Phase 1: S2^T = KT x Q^T, single-pass fp16 ----
    float16 acc[4];
    #pragma unroll
    for (int m = 0; m < 4; ++m) acc[m] = (float16)(0.0f);

    half8 ah[2][4];
    #pragma unroll
    for (int m = 0; m < 4; ++m)
        ah[0][m] = *(const half8*)(ktp + (m * 8) * 1024 + lo16);
    #pragma unroll
    for (int ks = 0; ks < 8; ++ks) {
        const int cur = ks & 1, nxt = cur ^ 1;
        if (ks < 7) {
            #pragma unroll
            for (int m = 0; m < 4; ++m)
                ah[nxt][m] = *(const half8*)(ktp + (m * 8 + ks + 1) * 1024 + lo16);
        }
        half8 bh = *(const half8*)(qrp + ((2 * ks + H) ^ (ln & 15)) * 16);
        #pragma unroll
        for (int m = 0; m < 4; ++m) acc[m] = mfma_f16(ah[cur][m], bh, acc[m]);
    }

    // ---- prefetch VT t=0 ----
    half8 av[2][4];
    #pragma unroll
    for (int dm = 0; dm < 4; ++dm)
        av[0][dm] = *(const half8*)(vtp + (dm * 8) * 1024 + lo16);

    // ---- add exact rank-1 term: acc[m][4g+i] += ksum[32m+8g+4H+i] * qsum[l] ----
    const float qs = qsum_s[wave * 32 + ln];
    #pragma unroll
    for (int m = 0; m < 4; ++m)
        #pragma unroll
        for (int g = 0; g < 4; ++g) {
            float4 k4 = *(const float4*)&ksum_s[m * 32 + g * 8 + H * 4];
            acc[m][4 * g + 0] = fmaf(k4.x, qs, acc[m][4 * g + 0]);
            acc[m][4 * g + 1] = fmaf(k4.y, qs, acc[m][4 * g + 1]);
            acc[m][4 * g + 2] = fmaf(k4.z, qs, acc[m][4 * g + 2]);
            acc[m][4 * g + 3] = fmaf(k4.w, qs, acc[m][4 * g + 3]);
        }

    // ---- softmax over j: 64 in-lane + partner half ----
    float mx = -1e30f;
    #pragma unroll
    for (int m = 0; m < 4; ++m)
        #pragma unroll
        for (int r = 0; r < 16; ++r) mx = fmaxf(mx, acc[m][r]);
    mx = fmaxf(mx, __shfl_xor(mx, 32, 64));
    float sum = 0.0f;
    #pragma unroll
    for (int m = 0; m < 4; ++m)
        #pragma unroll
        for (int r = 0; r < 16; ++r) {
            float e = __expf(acc[m][r] - mx);
            acc[m][r] = e;
            sum += e;
        }
    sum += __shfl_xor(sum, 32, 64);
    const float inv = 1.0f / sum;

    // pack P^T rows to fp16 pairs
    unsigned pk[4][8];
    #pragma unroll
    for (int m = 0; m < 4; ++m)
        #pragma unroll
        for (int rr = 0; rr < 8; ++rr) {
            PU pu;
            pu.h[0] = (_Float16)(acc[m][2 * rr] * inv);
            pu.h[1] = (_Float16)(acc[m][2 * rr + 1] * inv);
            pk[m][rr] = pu.u;
        }

    // ---- Phase 2: out^T = VT x P^T (B-frags from regs via 2 shuffles) ----
    float16 oacc[4];
    #pragma unroll
    for (int m = 0; m < 4; ++m) oacc[m] = (float16)(0.0f);

    #pragma unroll
    for (int t = 0; t < 8; ++t) {
        const int cur = t & 1, nxt = cur ^ 1;
        if (t < 7) {
            #pragma unroll
            for (int dm = 0; dm < 4; ++dm)
                av[nxt][dm] = *(const half8*)(vtp + (dm * 8 + t + 1) * 1024 + lo16);
        }
        const int m = t >> 1;
        const int c = 4 * (t & 1);
        unsigned p0 = pk[m][c], p1 = pk[m][c + 1], p2 = pk[m][c + 2], p3 = pk[m][c + 3];
        unsigned a0 = H ? p2 : p0, a1 = H ? p3 : p1;
        unsigned s0 = H ? p0 : p2, s1 = H ? p1 : p3;
        unsigned r0 = (unsigned)__shfl_xor((int)s0, 32, 64);
        unsigned r1 = (unsigned)__shfl_xor((int)s1, 32, 64);
        H8U bf;
        bf.w[0] = H ? r0 : a0;
        bf.w[1] = H ? r1 : a1;
        bf.w[2] = H ? a0 : r0;
        bf.w[3] = H ? a1 : r1;
        #pragma unroll
        for (int dm = 0; dm < 4; ++dm)
            oacc[dm] = mfma_f16(av[cur][dm], bf.v, oacc[dm]);
    }

    // ---- epilogue: out^T C-layout -> coalesced float4 stores ----
    #pragma unroll
    for (int dm = 0; dm < 4; ++dm)
        #pragma unroll
        for (int g = 0; g < 4; ++g) {
            float4 v = make_float4(oacc[dm][4 * g], oacc[dm][4 * g + 1],
                                   oacc[dm][4 * g + 2], oacc[dm][4 * g + 3]);
            *(float4*)(ob + ln * SDIM + dm * 32 + g * 8 + H * 4) = v;
        }
}

extern "C" void kernel_launch(void* const* d_in, const int* in_sizes, int n_in,
                              void* d_out, int out_size, void* d_ws, size_t ws_size,
                              hipStream_t stream) {
    const float* q    = (const float*)d_in[0];
    const float* keys = (const float*)d_in[1];
    const float* vals = (const float*)d_in[2];
    float* out = (float*)d_out;
    char*  ws  = (char*)d_ws;   // needs ~2.02 MB

    prep_kernel<<<BATCH * 2, 256, 0, stream>>>(keys, vals, ws);
    attn_kernel<<<BATCH * (LDIM / 128), 256, 0, stream>>>(q, ws, out);
}